// Round 11
// baseline (1086.959 us; speedup 1.0000x reference)
//
#include <hip/hip_runtime.h>
#include <hip/hip_bf16.h>
#include <math.h>

// Problem constants
#define Dn 6
#define Bn 32
#define Cn 384
#define Hn 6
#define HDn 64
#define FFn 1536
#define NCn 10
#define IMGn 224
#define Nn 197
#define NPATCH 196
#define RP 256            // padded rows per batch (X, O, FFb)
#define TROWS 6400        // packed T/QKV rows: 32*197=6304, padded to 6400
#define SCALEf 0.125f
#define EPSf 1e-6f

typedef unsigned short u16;
typedef __attribute__((ext_vector_type(8))) short short8;
typedef __attribute__((ext_vector_type(4))) float f32x4;

__device__ __forceinline__ u16 f2bf(float f) {
    unsigned u = __float_as_uint(f);
    return (u16)((u + 0x7FFFu + ((u >> 16) & 1u)) >> 16);
}

__device__ __forceinline__ void gload16(const void* g, void* l) {
    __builtin_amdgcn_global_load_lds((const __attribute__((address_space(1))) void*)g,
                                     (__attribute__((address_space(3))) void*)l, 16, 0, 0);
}

// ---------------------------------------------------------------------------
// cvt f32 -> bf16, 8 elems/thread
// ---------------------------------------------------------------------------
__global__ __launch_bounds__(256) void cvtbf_kernel(const float* __restrict__ in,
                                                    u16* __restrict__ out) {
    long off = ((long)blockIdx.x * 256 + threadIdx.x) * 8;
    float4 v0 = *(const float4*)(in + off);
    float4 v1 = *(const float4*)(in + off + 4);
    short8 p;
    p[0] = f2bf(v0.x); p[1] = f2bf(v0.y); p[2] = f2bf(v0.z); p[3] = f2bf(v0.w);
    p[4] = f2bf(v1.x); p[5] = f2bf(v1.y); p[6] = f2bf(v1.z); p[7] = f2bf(v1.w);
    *(short8*)(out + off) = p;
}

// ---------------------------------------------------------------------------
// Per-layer masked-weight precompute. grid (2880, 3).
// seg0: proj (720 blocks), seg1: fc1, seg2: fc2. 8 elems/thread, plain loads.
// ---------------------------------------------------------------------------
__global__ __launch_bounds__(256) void maskmul3_kernel(
    const float* __restrict__ pw, const float* __restrict__ mp,
    const float* __restrict__ f1w, const float* __restrict__ mf1,
    const float* __restrict__ f2w, const float* __restrict__ mf2,
    u16* __restrict__ WMp, u16* __restrict__ WMf1, u16* __restrict__ WMf2) {
    const int seg = blockIdx.y;
    const unsigned bx = blockIdx.x;
    const float* W; const float* M; u16* O; int wi;
    if (seg == 0) {
        if (bx >= 720u) return;
        unsigned cls = bx / 72u;
        wi = (int)(bx - cls * 72u) * 2048 + threadIdx.x * 8;
        W = pw;
        M = mp + (long)cls * (Cn * Cn);
        O = WMp + (long)cls * (Cn * Cn);
    } else if (seg == 1) {
        unsigned cls = bx / 288u;
        wi = (int)(bx - cls * 288u) * 2048 + threadIdx.x * 8;
        W = f1w;
        M = mf1 + (long)cls * (FFn * Cn);
        O = WMf1 + (long)cls * (FFn * Cn);
    } else {
        unsigned cls = bx / 288u;
        wi = (int)(bx - cls * 288u) * 2048 + threadIdx.x * 8;
        W = f2w;
        M = mf2 + (long)cls * (Cn * FFn);
        O = WMf2 + (long)cls * (Cn * FFn);
    }
    float4 w0 = *(const float4*)(W + wi);
    float4 w1 = *(const float4*)(W + wi + 4);
    float4 m0 = *(const float4*)(M + wi);
    float4 m1 = *(const float4*)(M + wi + 4);
    short8 p;
    p[0] = f2bf(w0.x * m0.x); p[1] = f2bf(w0.y * m0.y);
    p[2] = f2bf(w0.z * m0.z); p[3] = f2bf(w0.w * m0.w);
    p[4] = f2bf(w1.x * m1.x); p[5] = f2bf(w1.y * m1.y);
    p[6] = f2bf(w1.z * m1.z); p[7] = f2bf(w1.w * m1.w);
    *(short8*)(O + wi) = p;
}

// ---------------------------------------------------------------------------
// im2col -> bf16
// ---------------------------------------------------------------------------
__global__ __launch_bounds__(256) void im2col_kernel(const float* __restrict__ x,
                                                     u16* __restrict__ col) {
    long idx = (long)blockIdx.x * 256 + threadIdx.x;
    int k = (int)(idx % 768);
    long row = idx / 768;
    int b = (int)(row / NPATCH), p = (int)(row % NPATCH);
    int i = k / 256, r = k % 256, ph = r / 16, pw = r % 16;
    int py = p / 14, px = p % 14;
    col[idx] = f2bf(x[(((long)b * 3 + i) * IMGn + py * 16 + ph) * IMGn + px * 16 + pw]);
}

// ---------------------------------------------------------------------------
// assemble x (f32, padded rows): row 0 = cls+pos, rows 1..196 = patch+pos
// ---------------------------------------------------------------------------
__global__ __launch_bounds__(256) void assemble_kernel(const float* __restrict__ tmp,
                                                       const float* __restrict__ cls_token,
                                                       const float* __restrict__ pos,
                                                       float* __restrict__ x) {
    long idx = (long)blockIdx.x * 256 + threadIdx.x;
    int c = (int)(idx % Cn);
    long rem = idx / Cn;
    int n = (int)(rem % Nn);
    int b = (int)(rem / Nn);
    float v;
    if (n == 0) v = cls_token[c];
    else v = tmp[((long)b * NPATCH + (n - 1)) * Cn + c];
    x[((long)b * RP + n) * Cn + c] = v + pos[n * Cn + c];
}

// ---------------------------------------------------------------------------
// Zero X pad rows (b<Bn) and packed-Tp tail rows (b==Bn).
// ---------------------------------------------------------------------------
__global__ __launch_bounds__(256) void pad_zero(float* __restrict__ X,
                                                u16* __restrict__ Tp) {
    int b = blockIdx.x;
    int tid = threadIdx.x;
    if (b == Bn) {
        u16* t0 = Tp + (long)Bn * Nn * Cn;
        for (int i = tid; i < (TROWS - Bn * Nn) * Cn; i += 256) t0[i] = 0;
        return;
    }
    float* Xb = X + ((long)b * RP + Nn) * Cn;
    for (int i = tid; i < (RP - Nn) * Cn; i += 256) Xb[i] = 0.f;
}

// ---------------------------------------------------------------------------
// LayerNorm: X f32 (padded RP rows) -> Tp bf16 (packed Nn rows). 1 wave/row.
// ---------------------------------------------------------------------------
__global__ __launch_bounds__(64) void ln_kernel(const float* __restrict__ x,
                                                const float* __restrict__ w,
                                                const float* __restrict__ b,
                                                u16* __restrict__ out) {
    long blk = blockIdx.x;
    int bb = (int)(blk / Nn), n = (int)(blk % Nn);
    const float* xr = x + ((long)bb * RP + n) * Cn;
    u16* orow = out + ((long)bb * Nn + n) * Cn;
    int lane = threadIdx.x;
    float v[6];
    float s = 0.f, ss = 0.f;
#pragma unroll
    for (int j = 0; j < 6; ++j) {
        v[j] = xr[lane + 64 * j];
        s += v[j];
        ss += v[j] * v[j];
    }
#pragma unroll
    for (int off = 32; off >= 1; off >>= 1) {
        s += __shfl_xor(s, off);
        ss += __shfl_xor(ss, off);
    }
    float m = s * (1.0f / Cn);
    float var = ss * (1.0f / Cn) - m * m;
    float rstd = rsqrtf(var + EPSf);
#pragma unroll
    for (int j = 0; j < 6; ++j) {
        int c = lane + 64 * j;
        orow[c] = f2bf((v[j] - m) * rstd * w[c] + b[c]);
    }
}

// ---------------------------------------------------------------------------
// bf16 MFMA GEMM, tile MTx128, K-step 32, double-buffered global_load_lds.
// EPI 0: bf16 store. EPI 1: gelu+bf16. EPI 2: f32 += (plain). EPI 3: f32 store.
// grid: (M/MT, N/128, Z)
// ---------------------------------------------------------------------------
template <int EPI, int MT>
__global__ __launch_bounds__(256) void gemm_bf16(
    const u16* __restrict__ A, long strideA,
    const u16* __restrict__ Wb, long wClassStride,
    const int* __restrict__ y,
    const float* __restrict__ bias,
    void* __restrict__ OutV, long strideO,
    int Nout, int Ktot) {
    const int bz = blockIdx.z;
    A += (long)bz * strideA;
    const u16* Wp = Wb + (y ? (long)y[bz] * wClassStride : 0);

    constexpr int ASUB = MT / 16;
    constexpr int AI = MT / 32;
    __shared__ alignas(16) u16 Ab[2][ASUB * 512];
    __shared__ alignas(16) u16 Bb[2][4096];

    const int tid = threadIdx.x;
    const int lane = tid & 63;
    const int w = tid >> 6;
    const int wr = w >> 1, wc = w & 1;
    const int m0 = blockIdx.x * MT;
    const int n0 = blockIdx.y * 128;
    const int r15 = lane & 15, oct = lane >> 4;

    auto STAGE = [&](int k0, int bf) {
        {
            int s0 = 2 * w;
            const u16* b0 = Wp + (long)(n0 + 16 * s0 + r15) * Ktot + k0 + oct * 8;
            gload16(b0, &Bb[bf][s0 * 512]);
            gload16(b0 + 16 * (long)Ktot, &Bb[bf][(s0 + 1) * 512]);
        }
        if (MT == 128) {
            int s0 = 2 * w;
            const u16* a0 = A + (long)(m0 + 16 * s0 + r15) * Ktot + k0 + oct * 8;
            gload16(a0, &Ab[bf][s0 * 512]);
            gload16(a0 + 16 * (long)Ktot, &Ab[bf][(s0 + 1) * 512]);
        } else {
            const u16* a0 = A + (long)(m0 + 16 * w + r15) * Ktot + k0 + oct * 8;
            gload16(a0, &Ab[bf][w * 512]);
        }
    };

    f32x4 acc[AI][4];
#pragma unroll
    for (int i = 0; i < AI; ++i)
#pragma unroll
        for (int j = 0; j < 4; ++j) acc[i][j] = (f32x4){0.f, 0.f, 0.f, 0.f};

    const int nsteps = Ktot / 32;
    STAGE(0, 0);
    __syncthreads();
    int cur = 0;
    for (int t = 0; t < nsteps; ++t) {
        if (t + 1 < nsteps) STAGE((t + 1) * 32, cur ^ 1);
        short8 af[AI], bfr[4];
#pragma unroll
        for (int i = 0; i < AI; ++i)
            af[i] = *(const short8*)(&Ab[cur][(wr * AI + i) * 512 + lane * 8]);
#pragma unroll
        for (int j = 0; j < 4; ++j)
            bfr[j] = *(const short8*)(&Bb[cur][(wc * 4 + j) * 512 + lane * 8]);
#pragma unroll
        for (int i = 0; i < AI; ++i)
#pragma unroll
            for (int j = 0; j < 4; ++j)
                acc[i][j] = __builtin_amdgcn_mfma_f32_16x16x32_bf16(af[i], bfr[j], acc[i][j], 0, 0, 0);
        __syncthreads();
        cur ^= 1;
    }

    // epilogue: D frag mapping col=lane&15, row=(lane>>4)*4+r
    const int lr = lane >> 4;
    const int lc = lane & 15;
#pragma unroll
    for (int i = 0; i < AI; ++i) {
#pragma unroll
        for (int j = 0; j < 4; ++j) {
            int colg = n0 + (wc * 4 + j) * 16 + lc;
            float bv = bias ? bias[colg] : 0.f;
#pragma unroll
            for (int r = 0; r < 4; ++r) {
                int m = m0 + (wr * AI + i) * 16 + lr * 4 + r;
                float v = acc[i][j][r] + bv;
                long oi = (long)m * Nout + colg;
                if (EPI == 0) {
                    ((u16*)OutV + (long)bz * strideO)[oi] = f2bf(v);
                } else if (EPI == 1) {
                    v = 0.5f * v * (1.0f + erff(v * 0.70710678118654752440f));
                    ((u16*)OutV + (long)bz * strideO)[oi] = f2bf(v);
                } else if (EPI == 2) {
                    ((float*)OutV + (long)bz * strideO)[oi] += v;
                } else {
                    ((float*)OutV + (long)bz * strideO)[oi] = v;
                }
            }
        }
    }
}

// ---------------------------------------------------------------------------
// Fused attention on bf16 packed QKV (197 rows/batch). O padded.
// ---------------------------------------------------------------------------
__global__ __launch_bounds__(256) void attn_fused(const u16* __restrict__ qkv,
                                                  const float* __restrict__ ma,
                                                  const int* __restrict__ y,
                                                  u16* __restrict__ O) {
    const int it = blockIdx.x;
    const int bh = blockIdx.y;
    const int h = bh % Hn, b = bh / Hn;
    const int i0 = it * 64;
    const int tid = threadIdx.x, lane = tid & 63, w = tid >> 6;
    const int lg = lane >> 4, lc = lane & 15;

    __shared__ alignas(16) u16 SH[31744];
    u16* Qb = SH;
    u16* Kb = SH + 4096;
    u16* Vb = SH;
    u16* Pb = SH + 17408;

    const u16* qkv_b = qkv + (long)b * Nn * (3 * Cn);
    const int r15 = lane & 15;
    const int oct = lane >> 4;

#pragma unroll
    for (int si = 0; si < 2; ++si) {
        int s = w * 2 + si;
        int r = (s >> 1) * 16 + r15;
        int g = (s & 1) * 4 + oct;
        const u16* src = qkv_b + (long)(i0 + r) * (3 * Cn) + h * HDn + g * 8;
        gload16(src, Qb + s * 512);
    }
    for (int s = w; s < 26; s += 4) {
        int c = (s >> 1) * 16 + r15;
        int g = (s & 1) * 4 + oct;
        const u16* src = qkv_b + (long)c * (3 * Cn) + Cn + h * HDn + g * 8;
        gload16(src, Kb + s * 512);
    }
    __syncthreads();

    f32x4 s[13];
#pragma unroll
    for (int jf = 0; jf < 13; ++jf) s[jf] = (f32x4){0.f, 0.f, 0.f, 0.f};
    {
        short8 a0 = *(const short8*)(Qb + (w * 2 + 0) * 512 + lane * 8);
        short8 a1 = *(const short8*)(Qb + (w * 2 + 1) * 512 + lane * 8);
#pragma unroll
        for (int jf = 0; jf < 13; ++jf) {
            short8 b0 = *(const short8*)(Kb + (jf * 2 + 0) * 512 + lane * 8);
            short8 b1 = *(const short8*)(Kb + (jf * 2 + 1) * 512 + lane * 8);
            s[jf] = __builtin_amdgcn_mfma_f32_16x16x32_bf16(a0, b0, s[jf], 0, 0, 0);
            s[jf] = __builtin_amdgcn_mfma_f32_16x16x32_bf16(a1, b1, s[jf], 0, 0, 0);
        }
    }

#pragma unroll
    for (int r = 0; r < 4; ++r) {
        float mx = -1e30f;
#pragma unroll
        for (int jf = 0; jf < 13; ++jf) {
            float v = s[jf][r] * SCALEf;
            if (jf * 16 + lc > 196) v = -1e30f;
            mx = fmaxf(mx, v);
        }
#pragma unroll
        for (int off = 1; off <= 8; off <<= 1) mx = fmaxf(mx, __shfl_xor(mx, off));
        float sum = 0.f;
#pragma unroll
        for (int jf = 0; jf < 13; ++jf) {
            float e = (jf * 16 + lc <= 196) ? __expf(s[jf][r] * SCALEf - mx) : 0.f;
            s[jf][r] = e;
            sum += e;
        }
#pragma unroll
        for (int off = 1; off <= 8; off <<= 1) sum += __shfl_xor(sum, off);
        float inv = 1.0f / sum;
#pragma unroll
        for (int jf = 0; jf < 13; ++jf) s[jf][r] *= inv;
    }
    __syncthreads();

    if (lane < 32) {
        short8 z = {0, 0, 0, 0, 0, 0, 0, 0};
        *(short8*)(Pb + (w * 7 + 6) * 512 + (32 + lane) * 8) = z;
    }
#pragma unroll
    for (int jf = 0; jf < 13; ++jf) {
#pragma unroll
        for (int r = 0; r < 4; ++r) {
            int col = jf * 16 + lc;
            int row = lg * 4 + r;
            Pb[(w * 7 + (col >> 5)) * 512 + (((col >> 3) & 3) * 16 + row) * 8 + (col & 7)] =
                (u16)f2bf(s[jf][r]);
        }
    }
    // ---- stage V (224 x 64): coalesced 16B global loads + LDS transpose
    {
        const u16* vbase = qkv_b + 2 * Cn + h * HDn;
        const int jr = tid >> 3;          // 0..31: row within iteration
        const int d0 = (tid & 7) * 8;     // col octet 0,8,...,56
        const int dsub = d0 >> 4;         // df index 0..3
        const int chi = d0 & 15;          // 0 or 8
        const int g = jr >> 3;            // k-octet group within subtile
        const int e = jr & 7;             // elem within octet
#pragma unroll
        for (int itv = 0; itv < 7; ++itv) {
            int j = jr + itv * 32;        // 0..223 (pad rows hold finite bias vals)
            short8 v = *(const short8*)(vbase + (long)j * (3 * Cn) + d0);
            u16* dst = Vb + dsub * (7 * 512) + itv * 512 + (g * 16 + chi) * 8 + e;
#pragma unroll
            for (int t = 0; t < 8; ++t)
                dst[t * 8] = (u16)v[t];
        }
    }
    __syncthreads();

    f32x4 o[4];
#pragma unroll
    for (int df = 0; df < 4; ++df) o[df] = (f32x4){0.f, 0.f, 0.f, 0.f};
#pragma unroll
    for (int ks = 0; ks < 7; ++ks) {
        short8 pa = *(const short8*)(Pb + (w * 7 + ks) * 512 + lane * 8);
#pragma unroll
        for (int df = 0; df < 4; ++df) {
            short8 vb = *(const short8*)(Vb + (df * 7 + ks) * 512 + lane * 8);
            o[df] = __builtin_amdgcn_mfma_f32_16x16x32_bf16(pa, vb, o[df], 0, 0, 0);
        }
    }

    const float* mar = ma + (long)y[b] * (Hn * HDn) + h * HDn;
#pragma unroll
    for (int df = 0; df < 4; ++df) {
        int dcol = df * 16 + lc;
        float mk = mar[dcol];
#pragma unroll
        for (int r = 0; r < 4; ++r) {
            int i = i0 + w * 16 + lg * 4 + r;
            O[((long)b * RP + i) * Cn + h * HDn + dcol] = f2bf(o[df][r] * mk);
        }
    }
}

// ---------------------------------------------------------------------------
// Final: LN(x[b,0,:]) + head. One wave per b. X padded.
// ---------------------------------------------------------------------------
__global__ __launch_bounds__(64) void final_head(const float* __restrict__ x,
                                                 const float* __restrict__ nw,
                                                 const float* __restrict__ nb,
                                                 const float* __restrict__ hw,
                                                 const float* __restrict__ hb,
                                                 float* __restrict__ out) {
    int b = blockIdx.x;
    int lane = threadIdx.x;
    const float* xr = x + (long)b * RP * Cn;
    float v[6];
    float s = 0.f, ss = 0.f;
#pragma unroll
    for (int j = 0; j < 6; ++j) {
        v[j] = xr[lane + 64 * j];
        s += v[j];
        ss += v[j] * v[j];
    }
#pragma unroll
    for (int off = 32; off >= 1; off >>= 1) {
        s += __shfl_xor(s, off);
        ss += __shfl_xor(ss, off);
    }
    float m = s * (1.0f / Cn);
    float var = ss * (1.0f / Cn) - m * m;
    float rstd = rsqrtf(var + EPSf);
    float nvals[6];
#pragma unroll
    for (int j = 0; j < 6; ++j) {
        int c = lane + 64 * j;
        nvals[j] = (v[j] - m) * rstd * nw[c] + nb[c];
    }
    for (int c10 = 0; c10 < NCn; ++c10) {
        float p = 0.f;
#pragma unroll
        for (int j = 0; j < 6; ++j) p += nvals[j] * hw[(long)c10 * Cn + lane + 64 * j];
#pragma unroll
        for (int off = 32; off >= 1; off >>= 1) p += __shfl_xor(p, off);
        if (lane == 0) out[b * NCn + c10] = p + hb[c10];
    }
}

// ---------------------------------------------------------------------------
extern "C" void kernel_launch(void* const* d_in, const int* in_sizes, int n_in,
                              void* d_out, int out_size, void* d_ws, size_t ws_size,
                              hipStream_t stream) {
    const float* x_in     = (const float*)d_in[0];
    const int*   y        = (const int*)d_in[1];
    const float* patch_w  = (const float*)d_in[2];
    const float* patch_b  = (const float*)d_in[3];
    const float* cls_tok  = (const float*)d_in[4];
    const float* pos_emb  = (const float*)d_in[5];
    const float* n1_w     = (const float*)d_in[6];
    const float* n1_b     = (const float*)d_in[7];
    const float* qkv_w    = (const float*)d_in[8];
    const float* qkv_b    = (const float*)d_in[9];
    const float* proj_w   = (const float*)d_in[10];
    const float* proj_b   = (const float*)d_in[11];
    const float* mask_attn= (const float*)d_in[12];
    const float* mask_proj= (const float*)d_in[13];
    const float* n2_w     = (const float*)d_in[14];
    const float* n2_b     = (const float*)d_in[15];
    const float* fc1_w    = (const float*)d_in[16];
    const float* fc1_b    = (const float*)d_in[17];
    const float* fc2_w    = (const float*)d_in[18];
    const float* fc2_b    = (const float*)d_in[19];
    const float* mask_fc1 = (const float*)d_in[20];
    const float* mask_fc2 = (const float*)d_in[21];
    const float* norm_w   = (const float*)d_in[22];
    const float* norm_b   = (const float*)d_in[23];
    const float* head_w   = (const float*)d_in[24];
    const float* head_b   = (const float*)d_in[25];

    // ---- workspace layout ----
    char* base = (char*)d_ws;
    float* X    = (float*)base;   base += (long)Bn * RP * Cn * 4;
    u16*   Tp   = (u16*)base;     base += (long)TROWS * Cn * 2;          // packed
    u16*   QKV  = (u16*)base;     base += (long)TROWS * 3 * Cn * 2;      // packed
    u16*   O    = (u16*)base;     base += (long)Bn * RP * Cn * 2;
    u16*   FFb  = (u16*)base;     base += (long)Bn * RP * FFn * 2;
    u16*   COL  = (u16*)base;     base += (long)Bn * NPATCH * 768 * 2;
    u16*   WQ   = (u16*)base;     base += (long)Dn * 3 * Cn * Cn * 2;
    u16*   WP   = (u16*)base;     base += (long)Cn * 768 * 2;
    u16*   WMp  = (u16*)base;     base += (long)Dn * NCn * Cn * Cn * 2;
    u16*   WMf1 = (u16*)base;     base += (long)Dn * NCn * FFn * Cn * 2;
    u16*   WMf2 = (u16*)base;     base += (long)Dn * NCn * Cn * FFn * 2;
    float* PTMP = (float*)FFb;    // alias: patch-gemm f32 output, pre-loop only

    const long sX = (long)RP * Cn;      // X/O per-batch stride
    const long sTp = (long)Nn * Cn;     // packed T per-batch stride
    const long sF = (long)RP * FFn;

    // ---- prep ----
    cvtbf_kernel<<<1296, 256, 0, stream>>>(qkv_w, WQ);
    cvtbf_kernel<<<144, 256, 0, stream>>>(patch_w, WP);
    for (int l = 0; l < Dn; ++l) {
        maskmul3_kernel<<<dim3(2880, 3), 256, 0, stream>>>(
            proj_w + (long)l * Cn * Cn, mask_proj + (long)l * NCn * Cn * Cn,
            fc1_w + (long)l * FFn * Cn, mask_fc1 + (long)l * NCn * FFn * Cn,
            fc2_w + (long)l * Cn * FFn, mask_fc2 + (long)l * NCn * Cn * FFn,
            WMp + (long)l * NCn * Cn * Cn,
            WMf1 + (long)l * NCn * FFn * Cn,
            WMf2 + (long)l * NCn * Cn * FFn);
    }

    // ---- patch embed + pos ----
    im2col_kernel<<<18816, 256, 0, stream>>>(x_in, COL);
    gemm_bf16<3, 64><<<dim3(98, 3, 1), 256, 0, stream>>>(
        COL, 0, WP, 0, nullptr, patch_b, PTMP, 0, Cn, 768);
    assemble_kernel<<<9456, 256, 0, stream>>>(PTMP, cls_tok, pos_emb, X);
    pad_zero<<<Bn + 1, 256, 0, stream>>>(X, Tp);
    // Tp = LN1_0(X)
    ln_kernel<<<Bn * Nn, 64, 0, stream>>>(X, n1_w, n1_b, Tp);

    for (int l = 0; l < Dn; ++l) {
        const u16* WMp_l  = WMp  + (long)l * NCn * Cn * Cn;
        const u16* WMf1_l = WMf1 + (long)l * NCn * FFn * Cn;
        const u16* WMf2_l = WMf2 + (long)l * NCn * Cn * FFn;

        // QKV = Tp @ qw^T + qb   (packed M=6400, N=1152, K=384), MT=64
        gemm_bf16<0, 64><<<dim3(100, 9, 1), 256, 0, stream>>>(
            Tp, 0, WQ + (long)l * 3 * Cn * Cn, 0, nullptr, qkv_b + (long)l * 3 * Cn,
            QKV, 0, 3 * Cn, Cn);
        // fused attention (mask_attn epilogue), O padded
        attn_fused<<<dim3(4, Bn * Hn), 256, 0, stream>>>(
            QKV, mask_attn + (long)l * NCn * Hn * HDn, y, O);
        // X += O @ Wm_proj[y]^T + pb
        gemm_bf16<2, 64><<<dim3(4, 3, Bn), 256, 0, stream>>>(
            O, sX, WMp_l, (long)Cn * Cn, y, proj_b + l * Cn, X, sX, Cn, Cn);
        // Tp = LN2(X)
        ln_kernel<<<Bn * Nn, 64, 0, stream>>>(X, n2_w + l * Cn, n2_b + l * Cn, Tp);
        // FFb = gelu(Tp @ Wm_fc1[y]^T + f1b)
        gemm_bf16<1, 128><<<dim3(2, 12, Bn), 256, 0, stream>>>(
            Tp, sTp, WMf1_l, (long)FFn * Cn, y, fc1_b + (long)l * FFn, FFb, sF, FFn, Cn);
        // X += FFb @ Wm_fc2[y]^T + f2b
        gemm_bf16<2, 64><<<dim3(4, 3, Bn), 256, 0, stream>>>(
            FFb, sF, WMf2_l, (long)Cn * FFn, y, fc2_b + l * Cn, X, sX, Cn, FFn);
        // Tp = LN1_{l+1}(X)  (skip after last layer)
        if (l + 1 < Dn)
            ln_kernel<<<Bn * Nn, 64, 0, stream>>>(X, n1_w + (l + 1) * Cn, n1_b + (l + 1) * Cn, Tp);
    }

    final_head<<<Bn, 64, 0, stream>>>(X, norm_w, norm_b, head_w, head_b, (float*)d_out);
}

// Round 12
// 1053.065 us; speedup vs baseline: 1.0322x; 1.0322x over previous
//
#include <hip/hip_runtime.h>
#include <hip/hip_bf16.h>
#include <math.h>

// Problem constants
#define Dn 6
#define Bn 32
#define Cn 384
#define Hn 6
#define HDn 64
#define FFn 1536
#define NCn 10
#define IMGn 224
#define Nn 197
#define NPATCH 196
#define RP 256            // padded rows per batch (X, O, FFb)
#define TROWS 6400        // packed T/QKV rows: 32*197=6304, padded to 6400
#define SCALEf 0.125f
#define EPSf 1e-6f

typedef unsigned short u16;
typedef __attribute__((ext_vector_type(8))) short short8;
typedef __attribute__((ext_vector_type(4))) float f32x4;

__device__ __forceinline__ u16 f2bf(float f) {
    unsigned u = __float_as_uint(f);
    return (u16)((u + 0x7FFFu + ((u >> 16) & 1u)) >> 16);
}

__device__ __forceinline__ void gload16(const void* g, void* l) {
    __builtin_amdgcn_global_load_lds((const __attribute__((address_space(1))) void*)g,
                                     (__attribute__((address_space(3))) void*)l, 16, 0, 0);
}

// ---------------------------------------------------------------------------
// cvt f32 -> bf16, 8 elems/thread
// ---------------------------------------------------------------------------
__global__ __launch_bounds__(256) void cvtbf_kernel(const float* __restrict__ in,
                                                    u16* __restrict__ out) {
    long off = ((long)blockIdx.x * 256 + threadIdx.x) * 8;
    float4 v0 = *(const float4*)(in + off);
    float4 v1 = *(const float4*)(in + off + 4);
    short8 p;
    p[0] = f2bf(v0.x); p[1] = f2bf(v0.y); p[2] = f2bf(v0.z); p[3] = f2bf(v0.w);
    p[4] = f2bf(v1.x); p[5] = f2bf(v1.y); p[6] = f2bf(v1.z); p[7] = f2bf(v1.w);
    *(short8*)(out + off) = p;
}

// ---------------------------------------------------------------------------
// ALL-layer masked-weight precompute (one dispatch). grid (2880, 3, 6).
// seg0: proj (720 blocks), seg1: fc1, seg2: fc2. 8 elems/thread, plain loads.
// ---------------------------------------------------------------------------
__global__ __launch_bounds__(256) void maskmul_all(
    const float* __restrict__ pw, const float* __restrict__ mp,
    const float* __restrict__ f1w, const float* __restrict__ mf1,
    const float* __restrict__ f2w, const float* __restrict__ mf2,
    u16* __restrict__ WMp, u16* __restrict__ WMf1, u16* __restrict__ WMf2) {
    const int l = blockIdx.z;
    const int seg = blockIdx.y;
    const unsigned bx = blockIdx.x;
    const float* W; const float* M; u16* O; int wi;
    if (seg == 0) {
        if (bx >= 720u) return;
        unsigned cls = bx / 72u;
        wi = (int)(bx - cls * 72u) * 2048 + threadIdx.x * 8;
        W = pw + (long)l * (Cn * Cn);
        M = mp + ((long)l * NCn + cls) * (Cn * Cn);
        O = WMp + ((long)l * NCn + cls) * (Cn * Cn);
    } else if (seg == 1) {
        unsigned cls = bx / 288u;
        wi = (int)(bx - cls * 288u) * 2048 + threadIdx.x * 8;
        W = f1w + (long)l * (FFn * Cn);
        M = mf1 + ((long)l * NCn + cls) * (FFn * Cn);
        O = WMf1 + ((long)l * NCn + cls) * (FFn * Cn);
    } else {
        unsigned cls = bx / 288u;
        wi = (int)(bx - cls * 288u) * 2048 + threadIdx.x * 8;
        W = f2w + (long)l * (Cn * FFn);
        M = mf2 + ((long)l * NCn + cls) * (Cn * FFn);
        O = WMf2 + ((long)l * NCn + cls) * (Cn * FFn);
    }
    float4 w0 = *(const float4*)(W + wi);
    float4 w1 = *(const float4*)(W + wi + 4);
    float4 m0 = *(const float4*)(M + wi);
    float4 m1 = *(const float4*)(M + wi + 4);
    short8 p;
    p[0] = f2bf(w0.x * m0.x); p[1] = f2bf(w0.y * m0.y);
    p[2] = f2bf(w0.z * m0.z); p[3] = f2bf(w0.w * m0.w);
    p[4] = f2bf(w1.x * m1.x); p[5] = f2bf(w1.y * m1.y);
    p[6] = f2bf(w1.z * m1.z); p[7] = f2bf(w1.w * m1.w);
    *(short8*)(O + wi) = p;
}

// ---------------------------------------------------------------------------
// im2col -> bf16
// ---------------------------------------------------------------------------
__global__ __launch_bounds__(256) void im2col_kernel(const float* __restrict__ x,
                                                     u16* __restrict__ col) {
    long idx = (long)blockIdx.x * 256 + threadIdx.x;
    int k = (int)(idx % 768);
    long row = idx / 768;
    int b = (int)(row / NPATCH), p = (int)(row % NPATCH);
    int i = k / 256, r = k % 256, ph = r / 16, pw = r % 16;
    int py = p / 14, px = p % 14;
    col[idx] = f2bf(x[(((long)b * 3 + i) * IMGn + py * 16 + ph) * IMGn + px * 16 + pw]);
}

// ---------------------------------------------------------------------------
// assemble x (f32, padded rows): row 0 = cls+pos, rows 1..196 = patch+pos
// ---------------------------------------------------------------------------
__global__ __launch_bounds__(256) void assemble_kernel(const float* __restrict__ tmp,
                                                       const float* __restrict__ cls_token,
                                                       const float* __restrict__ pos,
                                                       float* __restrict__ x) {
    long idx = (long)blockIdx.x * 256 + threadIdx.x;
    int c = (int)(idx % Cn);
    long rem = idx / Cn;
    int n = (int)(rem % Nn);
    int b = (int)(rem / Nn);
    float v;
    if (n == 0) v = cls_token[c];
    else v = tmp[((long)b * NPATCH + (n - 1)) * Cn + c];
    x[((long)b * RP + n) * Cn + c] = v + pos[n * Cn + c];
}

// ---------------------------------------------------------------------------
// Zero X pad rows (b<Bn) and packed-Tp tail rows (b==Bn).
// ---------------------------------------------------------------------------
__global__ __launch_bounds__(256) void pad_zero(float* __restrict__ X,
                                                u16* __restrict__ Tp) {
    int b = blockIdx.x;
    int tid = threadIdx.x;
    if (b == Bn) {
        u16* t0 = Tp + (long)Bn * Nn * Cn;
        for (int i = tid; i < (TROWS - Bn * Nn) * Cn; i += 256) t0[i] = 0;
        return;
    }
    float* Xb = X + ((long)b * RP + Nn) * Cn;
    for (int i = tid; i < (RP - Nn) * Cn; i += 256) Xb[i] = 0.f;
}

// ---------------------------------------------------------------------------
// LayerNorm: X f32 (padded RP rows) -> Tp bf16 (packed Nn rows). 1 wave/row.
// ---------------------------------------------------------------------------
__global__ __launch_bounds__(64) void ln_kernel(const float* __restrict__ x,
                                                const float* __restrict__ w,
                                                const float* __restrict__ b,
                                                u16* __restrict__ out) {
    long blk = blockIdx.x;
    int bb = (int)(blk / Nn), n = (int)(blk % Nn);
    const float* xr = x + ((long)bb * RP + n) * Cn;
    u16* orow = out + ((long)bb * Nn + n) * Cn;
    int lane = threadIdx.x;
    float v[6];
    float s = 0.f, ss = 0.f;
#pragma unroll
    for (int j = 0; j < 6; ++j) {
        v[j] = xr[lane + 64 * j];
        s += v[j];
        ss += v[j] * v[j];
    }
#pragma unroll
    for (int off = 32; off >= 1; off >>= 1) {
        s += __shfl_xor(s, off);
        ss += __shfl_xor(ss, off);
    }
    float m = s * (1.0f / Cn);
    float var = ss * (1.0f / Cn) - m * m;
    float rstd = rsqrtf(var + EPSf);
#pragma unroll
    for (int j = 0; j < 6; ++j) {
        int c = lane + 64 * j;
        orow[c] = f2bf((v[j] - m) * rstd * w[c] + b[c]);
    }
}

// ---------------------------------------------------------------------------
// bf16 MFMA GEMM, tile MTx128, K-step 32, double-buffered global_load_lds.
// EPI 0: bf16 store. EPI 1: gelu+bf16. EPI 2: f32 += (plain). EPI 3: f32 store.
// grid: (M/MT, N/128, Z)
// ---------------------------------------------------------------------------
template <int EPI, int MT>
__global__ __launch_bounds__(256) void gemm_bf16(
    const u16* __restrict__ A, long strideA,
    const u16* __restrict__ Wb, long wClassStride,
    const int* __restrict__ y,
    const float* __restrict__ bias,
    void* __restrict__ OutV, long strideO,
    int Nout, int Ktot) {
    const int bz = blockIdx.z;
    A += (long)bz * strideA;
    const u16* Wp = Wb + (y ? (long)y[bz] * wClassStride : 0);

    constexpr int ASUB = MT / 16;
    constexpr int AI = MT / 32;
    __shared__ alignas(16) u16 Ab[2][ASUB * 512];
    __shared__ alignas(16) u16 Bb[2][4096];

    const int tid = threadIdx.x;
    const int lane = tid & 63;
    const int w = tid >> 6;
    const int wr = w >> 1, wc = w & 1;
    const int m0 = blockIdx.x * MT;
    const int n0 = blockIdx.y * 128;
    const int r15 = lane & 15, oct = lane >> 4;

    auto STAGE = [&](int k0, int bf) {
        {
            int s0 = 2 * w;
            const u16* b0 = Wp + (long)(n0 + 16 * s0 + r15) * Ktot + k0 + oct * 8;
            gload16(b0, &Bb[bf][s0 * 512]);
            gload16(b0 + 16 * (long)Ktot, &Bb[bf][(s0 + 1) * 512]);
        }
        if (MT == 128) {
            int s0 = 2 * w;
            const u16* a0 = A + (long)(m0 + 16 * s0 + r15) * Ktot + k0 + oct * 8;
            gload16(a0, &Ab[bf][s0 * 512]);
            gload16(a0 + 16 * (long)Ktot, &Ab[bf][(s0 + 1) * 512]);
        } else {
            const u16* a0 = A + (long)(m0 + 16 * w + r15) * Ktot + k0 + oct * 8;
            gload16(a0, &Ab[bf][w * 512]);
        }
    };

    f32x4 acc[AI][4];
#pragma unroll
    for (int i = 0; i < AI; ++i)
#pragma unroll
        for (int j = 0; j < 4; ++j) acc[i][j] = (f32x4){0.f, 0.f, 0.f, 0.f};

    const int nsteps = Ktot / 32;
    STAGE(0, 0);
    __syncthreads();
    int cur = 0;
    for (int t = 0; t < nsteps; ++t) {
        if (t + 1 < nsteps) STAGE((t + 1) * 32, cur ^ 1);
        short8 af[AI], bfr[4];
#pragma unroll
        for (int i = 0; i < AI; ++i)
            af[i] = *(const short8*)(&Ab[cur][(wr * AI + i) * 512 + lane * 8]);
#pragma unroll
        for (int j = 0; j < 4; ++j)
            bfr[j] = *(const short8*)(&Bb[cur][(wc * 4 + j) * 512 + lane * 8]);
#pragma unroll
        for (int i = 0; i < AI; ++i)
#pragma unroll
            for (int j = 0; j < 4; ++j)
                acc[i][j] = __builtin_amdgcn_mfma_f32_16x16x32_bf16(af[i], bfr[j], acc[i][j], 0, 0, 0);
        __syncthreads();
        cur ^= 1;
    }

    // epilogue: D frag mapping col=lane&15, row=(lane>>4)*4+r
    const int lr = lane >> 4;
    const int lc = lane & 15;
#pragma unroll
    for (int i = 0; i < AI; ++i) {
#pragma unroll
        for (int j = 0; j < 4; ++j) {
            int colg = n0 + (wc * 4 + j) * 16 + lc;
            float bv = bias ? bias[colg] : 0.f;
#pragma unroll
            for (int r = 0; r < 4; ++r) {
                int m = m0 + (wr * AI + i) * 16 + lr * 4 + r;
                float v = acc[i][j][r] + bv;
                long oi = (long)m * Nout + colg;
                if (EPI == 0) {
                    ((u16*)OutV + (long)bz * strideO)[oi] = f2bf(v);
                } else if (EPI == 1) {
                    v = 0.5f * v * (1.0f + erff(v * 0.70710678118654752440f));
                    ((u16*)OutV + (long)bz * strideO)[oi] = f2bf(v);
                } else if (EPI == 2) {
                    ((float*)OutV + (long)bz * strideO)[oi] += v;
                } else {
                    ((float*)OutV + (long)bz * strideO)[oi] = v;
                }
            }
        }
    }
}

// ---------------------------------------------------------------------------
// Fused attention on bf16 packed QKV (197 rows/batch). O padded.
// ---------------------------------------------------------------------------
__global__ __launch_bounds__(256) void attn_fused(const u16* __restrict__ qkv,
                                                  const float* __restrict__ ma,
                                                  const int* __restrict__ y,
                                                  u16* __restrict__ O) {
    const int it = blockIdx.x;
    const int bh = blockIdx.y;
    const int h = bh % Hn, b = bh / Hn;
    const int i0 = it * 64;
    const int tid = threadIdx.x, lane = tid & 63, w = tid >> 6;
    const int lg = lane >> 4, lc = lane & 15;

    __shared__ alignas(16) u16 SH[31744];
    u16* Qb = SH;
    u16* Kb = SH + 4096;
    u16* Vb = SH;
    u16* Pb = SH + 17408;

    const u16* qkv_b = qkv + (long)b * Nn * (3 * Cn);
    const int r15 = lane & 15;
    const int oct = lane >> 4;

#pragma unroll
    for (int si = 0; si < 2; ++si) {
        int s = w * 2 + si;
        int r = (s >> 1) * 16 + r15;
        int g = (s & 1) * 4 + oct;
        const u16* src = qkv_b + (long)(i0 + r) * (3 * Cn) + h * HDn + g * 8;
        gload16(src, Qb + s * 512);
    }
    for (int s = w; s < 26; s += 4) {
        int c = (s >> 1) * 16 + r15;
        int g = (s & 1) * 4 + oct;
        const u16* src = qkv_b + (long)c * (3 * Cn) + Cn + h * HDn + g * 8;
        gload16(src, Kb + s * 512);
    }
    __syncthreads();

    f32x4 s[13];
#pragma unroll
    for (int jf = 0; jf < 13; ++jf) s[jf] = (f32x4){0.f, 0.f, 0.f, 0.f};
    {
        short8 a0 = *(const short8*)(Qb + (w * 2 + 0) * 512 + lane * 8);
        short8 a1 = *(const short8*)(Qb + (w * 2 + 1) * 512 + lane * 8);
#pragma unroll
        for (int jf = 0; jf < 13; ++jf) {
            short8 b0 = *(const short8*)(Kb + (jf * 2 + 0) * 512 + lane * 8);
            short8 b1 = *(const short8*)(Kb + (jf * 2 + 1) * 512 + lane * 8);
            s[jf] = __builtin_amdgcn_mfma_f32_16x16x32_bf16(a0, b0, s[jf], 0, 0, 0);
            s[jf] = __builtin_amdgcn_mfma_f32_16x16x32_bf16(a1, b1, s[jf], 0, 0, 0);
        }
    }

#pragma unroll
    for (int r = 0; r < 4; ++r) {
        float mx = -1e30f;
#pragma unroll
        for (int jf = 0; jf < 13; ++jf) {
            float v = s[jf][r] * SCALEf;
            if (jf * 16 + lc > 196) v = -1e30f;
            mx = fmaxf(mx, v);
        }
#pragma unroll
        for (int off = 1; off <= 8; off <<= 1) mx = fmaxf(mx, __shfl_xor(mx, off));
        float sum = 0.f;
#pragma unroll
        for (int jf = 0; jf < 13; ++jf) {
            float e = (jf * 16 + lc <= 196) ? __expf(s[jf][r] * SCALEf - mx) : 0.f;
            s[jf][r] = e;
            sum += e;
        }
#pragma unroll
        for (int off = 1; off <= 8; off <<= 1) sum += __shfl_xor(sum, off);
        float inv = 1.0f / sum;
#pragma unroll
        for (int jf = 0; jf < 13; ++jf) s[jf][r] *= inv;
    }
    __syncthreads();

    if (lane < 32) {
        short8 z = {0, 0, 0, 0, 0, 0, 0, 0};
        *(short8*)(Pb + (w * 7 + 6) * 512 + (32 + lane) * 8) = z;
    }
#pragma unroll
    for (int jf = 0; jf < 13; ++jf) {
#pragma unroll
        for (int r = 0; r < 4; ++r) {
            int col = jf * 16 + lc;
            int row = lg * 4 + r;
            Pb[(w * 7 + (col >> 5)) * 512 + (((col >> 3) & 3) * 16 + row) * 8 + (col & 7)] =
                (u16)f2bf(s[jf][r]);
        }
    }
    // ---- stage V (224 x 64): scalar gather + vector b128 LDS writes
    {
        const u16* vbase = qkv_b + 2 * Cn + h * HDn + (tid & 63);
        int d = tid & 63;
#pragma unroll
        for (int k = 0; k < 7; ++k) {
            int jo = (tid >> 6) + 4 * k;
            short8 p;
#pragma unroll
            for (int t = 0; t < 8; ++t)
                p[t] = (short)vbase[(long)(jo * 8 + t) * (3 * Cn)];
            *(short8*)(Vb + (d >> 4) * (7 * 512) + (jo >> 2) * 512 +
                       ((jo & 3) * 16 + (d & 15)) * 8) = p;
        }
    }
    __syncthreads();

    f32x4 o[4];
#pragma unroll
    for (int df = 0; df < 4; ++df) o[df] = (f32x4){0.f, 0.f, 0.f, 0.f};
#pragma unroll
    for (int ks = 0; ks < 7; ++ks) {
        short8 pa = *(const short8*)(Pb + (w * 7 + ks) * 512 + lane * 8);
#pragma unroll
        for (int df = 0; df < 4; ++df) {
            short8 vb = *(const short8*)(Vb + (df * 7 + ks) * 512 + lane * 8);
            o[df] = __builtin_amdgcn_mfma_f32_16x16x32_bf16(pa, vb, o[df], 0, 0, 0);
        }
    }

    const float* mar = ma + (long)y[b] * (Hn * HDn) + h * HDn;
#pragma unroll
    for (int df = 0; df < 4; ++df) {
        int dcol = df * 16 + lc;
        float mk = mar[dcol];
#pragma unroll
        for (int r = 0; r < 4; ++r) {
            int i = i0 + w * 16 + lg * 4 + r;
            O[((long)b * RP + i) * Cn + h * HDn + dcol] = f2bf(o[df][r] * mk);
        }
    }
}

// ---------------------------------------------------------------------------
// Final: LN(x[b,0,:]) + head. One wave per b. X padded.
// ---------------------------------------------------------------------------
__global__ __launch_bounds__(64) void final_head(const float* __restrict__ x,
                                                 const float* __restrict__ nw,
                                                 const float* __restrict__ nb,
                                                 const float* __restrict__ hw,
                                                 const float* __restrict__ hb,
                                                 float* __restrict__ out) {
    int b = blockIdx.x;
    int lane = threadIdx.x;
    const float* xr = x + (long)b * RP * Cn;
    float v[6];
    float s = 0.f, ss = 0.f;
#pragma unroll
    for (int j = 0; j < 6; ++j) {
        v[j] = xr[lane + 64 * j];
        s += v[j];
        ss += v[j] * v[j];
    }
#pragma unroll
    for (int off = 32; off >= 1; off >>= 1) {
        s += __shfl_xor(s, off);
        ss += __shfl_xor(ss, off);
    }
    float m = s * (1.0f / Cn);
    float var = ss * (1.0f / Cn) - m * m;
    float rstd = rsqrtf(var + EPSf);
    float nvals[6];
#pragma unroll
    for (int j = 0; j < 6; ++j) {
        int c = lane + 64 * j;
        nvals[j] = (v[j] - m) * rstd * nw[c] + nb[c];
    }
    for (int c10 = 0; c10 < NCn; ++c10) {
        float p = 0.f;
#pragma unroll
        for (int j = 0; j < 6; ++j) p += nvals[j] * hw[(long)c10 * Cn + lane + 64 * j];
#pragma unroll
        for (int off = 32; off >= 1; off >>= 1) p += __shfl_xor(p, off);
        if (lane == 0) out[b * NCn + c10] = p + hb[c10];
    }
}

// ---------------------------------------------------------------------------
extern "C" void kernel_launch(void* const* d_in, const int* in_sizes, int n_in,
                              void* d_out, int out_size, void* d_ws, size_t ws_size,
                              hipStream_t stream) {
    const float* x_in     = (const float*)d_in[0];
    const int*   y        = (const int*)d_in[1];
    const float* patch_w  = (const float*)d_in[2];
    const float* patch_b  = (const float*)d_in[3];
    const float* cls_tok  = (const float*)d_in[4];
    const float* pos_emb  = (const float*)d_in[5];
    const float* n1_w     = (const float*)d_in[6];
    const float* n1_b     = (const float*)d_in[7];
    const float* qkv_w    = (const float*)d_in[8];
    const float* qkv_b    = (const float*)d_in[9];
    const float* proj_w   = (const float*)d_in[10];
    const float* proj_b   = (const float*)d_in[11];
    const float* mask_attn= (const float*)d_in[12];
    const float* mask_proj= (const float*)d_in[13];
    const float* n2_w     = (const float*)d_in[14];
    const float* n2_b     = (const float*)d_in[15];
    const float* fc1_w    = (const float*)d_in[16];
    const float* fc1_b    = (const float*)d_in[17];
    const float* fc2_w    = (const float*)d_in[18];
    const float* fc2_b    = (const float*)d_in[19];
    const float* mask_fc1 = (const float*)d_in[20];
    const float* mask_fc2 = (const float*)d_in[21];
    const float* norm_w   = (const float*)d_in[22];
    const float* norm_b   = (const float*)d_in[23];
    const float* head_w   = (const float*)d_in[24];
    const float* head_b   = (const float*)d_in[25];

    // ---- workspace layout ----
    char* base = (char*)d_ws;
    float* X    = (float*)base;   base += (long)Bn * RP * Cn * 4;
    u16*   Tp   = (u16*)base;     base += (long)TROWS * Cn * 2;          // packed
    u16*   QKV  = (u16*)base;     base += (long)TROWS * 3 * Cn * 2;      // packed
    u16*   O    = (u16*)base;     base += (long)Bn * RP * Cn * 2;
    u16*   FFb  = (u16*)base;     base += (long)Bn * RP * FFn * 2;
    u16*   COL  = (u16*)base;     base += (long)Bn * NPATCH * 768 * 2;
    u16*   WQ   = (u16*)base;     base += (long)Dn * 3 * Cn * Cn * 2;
    u16*   WP   = (u16*)base;     base += (long)Cn * 768 * 2;
    u16*   WMp  = (u16*)base;     base += (long)Dn * NCn * Cn * Cn * 2;
    u16*   WMf1 = (u16*)base;     base += (long)Dn * NCn * FFn * Cn * 2;
    u16*   WMf2 = (u16*)base;     base += (long)Dn * NCn * Cn * FFn * 2;
    float* PTMP = (float*)FFb;    // alias: patch-gemm f32 output, pre-loop only

    const long sX = (long)RP * Cn;      // X/O per-batch stride
    const long sTp = (long)Nn * Cn;     // packed T per-batch stride
    const long sF = (long)RP * FFn;

    // ---- prep ----
    cvtbf_kernel<<<1296, 256, 0, stream>>>(qkv_w, WQ);
    cvtbf_kernel<<<144, 256, 0, stream>>>(patch_w, WP);
    maskmul_all<<<dim3(2880, 3, Dn), 256, 0, stream>>>(
        proj_w, mask_proj, fc1_w, mask_fc1, fc2_w, mask_fc2, WMp, WMf1, WMf2);

    // ---- patch embed + pos ----
    im2col_kernel<<<18816, 256, 0, stream>>>(x_in, COL);
    gemm_bf16<3, 64><<<dim3(98, 3, 1), 256, 0, stream>>>(
        COL, 0, WP, 0, nullptr, patch_b, PTMP, 0, Cn, 768);
    assemble_kernel<<<9456, 256, 0, stream>>>(PTMP, cls_tok, pos_emb, X);
    pad_zero<<<Bn + 1, 256, 0, stream>>>(X, Tp);
    // Tp = LN1_0(X)
    ln_kernel<<<Bn * Nn, 64, 0, stream>>>(X, n1_w, n1_b, Tp);

    for (int l = 0; l < Dn; ++l) {
        const u16* WMp_l  = WMp  + (long)l * NCn * Cn * Cn;
        const u16* WMf1_l = WMf1 + (long)l * NCn * FFn * Cn;
        const u16* WMf2_l = WMf2 + (long)l * NCn * Cn * FFn;

        // QKV = Tp @ qw^T + qb   (packed M=6400, N=1152, K=384), MT=128
        gemm_bf16<0, 128><<<dim3(50, 9, 1), 256, 0, stream>>>(
            Tp, 0, WQ + (long)l * 3 * Cn * Cn, 0, nullptr, qkv_b + (long)l * 3 * Cn,
            QKV, 0, 3 * Cn, Cn);
        // fused attention (mask_attn epilogue), O padded
        attn_fused<<<dim3(4, Bn * Hn), 256, 0, stream>>>(
            QKV, mask_attn + (long)l * NCn * Hn * HDn, y, O);
        // X += O @ Wm_proj[y]^T + pb
        gemm_bf16<2, 64><<<dim3(4, 3, Bn), 256, 0, stream>>>(
            O, sX, WMp_l, (long)Cn * Cn, y, proj_b + l * Cn, X, sX, Cn, Cn);
        // Tp = LN2(X)
        ln_kernel<<<Bn * Nn, 64, 0, stream>>>(X, n2_w + l * Cn, n2_b + l * Cn, Tp);
        // FFb = gelu(Tp @ Wm_fc1[y]^T + f1b)
        gemm_bf16<1, 128><<<dim3(2, 12, Bn), 256, 0, stream>>>(
            Tp, sTp, WMf1_l, (long)FFn * Cn, y, fc1_b + (long)l * FFn, FFb, sF, FFn, Cn);
        // X += FFb @ Wm_fc2[y]^T + f2b
        gemm_bf16<2, 64><<<dim3(4, 3, Bn), 256, 0, stream>>>(
            FFb, sF, WMf2_l, (long)Cn * FFn, y, fc2_b + l * Cn, X, sX, Cn, FFn);
        // Tp = LN1_{l+1}(X)  (skip after last layer)
        if (l + 1 < Dn)
            ln_kernel<<<Bn * Nn, 64, 0, stream>>>(X, n1_w + (l + 1) * Cn, n1_b + (l + 1) * Cn, Tp);
    }

    final_head<<<Bn, 64, 0, stream>>>(X, norm_w, norm_b, head_w, head_b, (float*)d_out);
}